// Round 8
// baseline (139.698 us; speedup 1.0000x reference)
//
#include <hip/hip_runtime.h>
#include <hip/hip_bf16.h>
#include <math.h>

#define NB 32768
#define DD 128
#define HH 512
#define EE 16
#define TM 64

typedef __attribute__((ext_vector_type(8))) short short8;
typedef __attribute__((ext_vector_type(4))) float f32x4;
typedef __attribute__((ext_vector_type(16))) float f32x16;

__device__ __forceinline__ unsigned short f2bf(float f) {
  union { float f; unsigned u; } v; v.f = f;
  unsigned r = v.u + 0x7fffu + ((v.u >> 16) & 1u);
  return (unsigned short)(r >> 16);
}

// Abramowitz-Stegun 7.1.26 erf, |eps| <= 1.5e-7; v_rcp (1 ULP) instead of IEEE div
__device__ __forceinline__ float fast_erf(float z) {
  float a = fabsf(z);
  float t = __builtin_amdgcn_rcpf(1.0f + 0.3275911f * a);
  float y = t * (0.254829592f + t * (-0.284496736f + t * (1.421413741f +
            t * (-1.453152027f + t * 1.061405429f))));
  float r = 1.0f - y * __expf(-a * a);
  return z < 0.0f ? -r : r;
}

// ---------------- fused prep: gate (blocks 0..511) + weight repack (512..1023) ----------
// Weights are repacked FRAGMENT-MAJOR for the no-LDS moe kernel: per expert, 256 blocks of
// 1KB; block = one 64-lane x 16B wave-load = one MFMA operand fragment.
//   w1 fragment (hc,t,ks), elem (l,j) = w1[e][d = ks*16+(l>>5)*8+j][h = hc*64+t*32+(l&31)]
//   w2 fragment (hc,s,dt), elem (l,j) = w2[e][h'][dout = dt*32+(l&31)],
//     h' = hc*64 + (s>>1)*32 + (j&3) + 8*((s&1)+2*(j>>2)) + 4*(l>>5)   (sigma, bijective)
// sigma aligns GEMM2's A-fragment k-slots with the register order of swapped-GEMM1's
// 32x32 D tile (row = (r&3)+8*(r>>2)+4*(lane>>5), col = lane&31  [m74/m101-verified]).
__global__ __launch_bounds__(256) void prep_kernel(
    const float* __restrict__ x, const float* __restrict__ wg,
    const float* __restrict__ bg, const float* __restrict__ w1,
    const float* __restrict__ w2, int* __restrict__ counts,
    int* __restrict__ rows, unsigned short* __restrict__ wP) {
  __shared__ __align__(16) char smem[50816];
  int tid = threadIdx.x;

  if (blockIdx.x >= 512) {
    // ---- fragment-major gather-repack (fully coalesced both sides, no LDS) ----
    int l = tid & 63, lc = l & 31, hi = l >> 5;
    int gw = (blockIdx.x - 512) * 4 + (tid >> 6);
    #pragma unroll
    for (int i = 0; i < 2; ++i) {
      int kb = gw * 2 + i;              // [0, 4096)
      int e = kb >> 8, v = kb & 255;
      float vals[8];
      if (v < 128) {
        int hc = v >> 4, t = (v >> 3) & 1, ks = v & 7;
        int h = hc * 64 + t * 32 + lc;
        const float* src = w1 + (size_t)e * DD * HH + h;
        int d0 = ks * 16 + hi * 8;
        #pragma unroll
        for (int j = 0; j < 8; ++j) vals[j] = src[(size_t)(d0 + j) * HH];
      } else {
        int b2 = v - 128;
        int hc = b2 >> 4, s = (b2 >> 2) & 3, dt = b2 & 3;
        int dout = dt * 32 + lc;
        const float* src = w2 + (size_t)e * HH * DD + dout;
        #pragma unroll
        for (int j = 0; j < 8; ++j) {
          int hp = hc * 64 + (s >> 1) * 32 + (j & 3) + 8 * ((s & 1) + 2 * (j >> 2)) + 4 * hi;
          vals[j] = src[(size_t)hp * DD];
        }
      }
      ushort4 p0, p1;
      p0.x = f2bf(vals[0]); p0.y = f2bf(vals[1]); p0.z = f2bf(vals[2]); p0.w = f2bf(vals[3]);
      p1.x = f2bf(vals[4]); p1.y = f2bf(vals[5]); p1.z = f2bf(vals[6]); p1.w = f2bf(vals[7]);
      unsigned short* dst = wP + (size_t)kb * 512 + l * 8;
      *(ushort4*)dst = p0;
      *(ushort4*)(dst + 4) = p1;
    }
    return;
  }

  // ---- gating: fp64 logits + block-aggregated bucket scatter (unchanged) ----
  float  (*sx)[132] = (float (*)[132])smem;
  double (*swg)[EE] = (double (*)[EE])(smem + 33792);
  int* lcnt  = (int*)(smem + 50176);
  int* gbase = lcnt + EE;
  int* lslot = gbase + EE;
  int* lexp  = lslot + 64;

  int base = blockIdx.x * 64;
  if (tid < EE) lcnt[tid] = 0;
  for (int i = tid; i < DD * EE; i += 256) swg[i >> 4][i & 15] = (double)wg[i];
  {
    int r = tid >> 2, c0 = (tid & 3) * 32;
    const float4* src = (const float4*)(x + (size_t)(base + r) * DD + c0);
    #pragma unroll
    for (int i = 0; i < 8; ++i)
      *(float4*)&sx[r][c0 + i * 4] = src[i];
  }
  __syncthreads();

  int r = tid >> 2;
  int e0 = (tid & 3) * 4;
  double acc[4];
  #pragma unroll
  for (int j = 0; j < 4; ++j) acc[j] = (double)bg[e0 + j];

  #pragma unroll 4
  for (int d = 0; d < DD; ++d) {
    double xv = (double)sx[r][d];
    #pragma unroll
    for (int j = 0; j < 4; ++j)
      acc[j] += xv * swg[d][e0 + j];
  }

  int beste = 0; double bestv = acc[0];
  #pragma unroll
  for (int j = 1; j < 4; ++j)
    if (acc[j] > bestv) { bestv = acc[j]; beste = j; }
  int ge = e0 + beste;

  #pragma unroll
  for (int off = 1; off < 4; off <<= 1) {
    double ov = __shfl_xor(bestv, off);
    int oe = __shfl_xor(ge, off);
    if (ov > bestv || (ov == bestv && oe < ge)) { bestv = ov; ge = oe; }
  }

  if ((tid & 3) == 0) {
    lslot[r] = atomicAdd(&lcnt[ge], 1);
    lexp[r] = ge;
  }
  __syncthreads();
  if (tid < EE && lcnt[tid] > 0)
    gbase[tid] = atomicAdd(&counts[tid], lcnt[tid]);
  __syncthreads();
  if ((tid & 3) == 0) {
    int e2 = lexp[r];
    rows[e2 * NB + gbase[e2] + lslot[r]] = base + r;
  }
}

// ---------------- grouped expert GEMM: out[r] = gelu(x[r]@w1[e]) @ w2[e] ----------------
// v10: ZERO LDS, ZERO barriers. One wave owns 32 rows end-to-end via 32x32x16 MFMA.
//   Weight fragments stream from L2 directly into registers (fragment-major layout ->
//   every load is 64 lanes x 16B coalesced). GEMM1 operand-swapped (H lane-local);
//   sigma permutation (baked into wP) aligns H's register order with GEMM2's A-frag.
//   Derived mappings (32x32 D: col=lane&31, row=(reg&3)+8*(reg>>2)+4*(lane>>5)):
//     GEMM1 D: a1[r] = H[m = lc][h = hc*64+t*32+(r&3)+8*(r>>2)+4*hi]
//     GEMM2 A: hf8[j] (s2 half) = gelu(a1[(j&3)|(s2<<2)|((j>>2)<<3)])  k = hi*8+j
//     GEMM2 D: acc2[dt][reg] = C[m = (reg&3)+8*(reg>>2)+4*hi][dout = dt*32+lc]
__global__ __launch_bounds__(128, 2) void moe_gemm(
    const float* __restrict__ x, const unsigned short* __restrict__ wP,
    const int* __restrict__ counts, const int* __restrict__ rows,
    float* __restrict__ out) {
  int e = blockIdx.x;
  int cnt = counts[e];
  int base = blockIdx.y * TM;
  if (base >= cnt) return;

  int tid = threadIdx.x;
  int wv = tid >> 6, l = tid & 63;
  int lc = l & 31, hi = l >> 5;
  int mb = base + wv * 32;            // this wave's 32-row tile
  if (mb >= cnt) return;              // wave-level exit: no barriers anywhere

  const unsigned short* we = wP + (size_t)e * 256 * 512;

  // X as GEMM1 B-operand: xa[ks] elem j = X[m=lc][d = ks*16 + hi*8 + j]
  short8 xa[8];
  {
    int ridx = mb + lc; if (ridx >= cnt) ridx = cnt - 1;
    int grow = rows[e * NB + ridx];
    const float* xr = x + (size_t)grow * DD + hi * 8;
    #pragma unroll
    for (int ks = 0; ks < 8; ++ks) {
      f32x4 v0 = *(const f32x4*)(xr + ks * 16);
      f32x4 v1 = *(const f32x4*)(xr + ks * 16 + 4);
      short8 a;
      a[0] = f2bf(v0[0]); a[1] = f2bf(v0[1]); a[2] = f2bf(v0[2]); a[3] = f2bf(v0[3]);
      a[4] = f2bf(v1[0]); a[5] = f2bf(v1[1]); a[6] = f2bf(v1[2]); a[7] = f2bf(v1[3]);
      xa[ks] = a;
    }
  }

  f32x16 acc2[4];
  #pragma unroll
  for (int dt = 0; dt < 4; ++dt)
    #pragma unroll
    for (int r = 0; r < 16; ++r) acc2[dt][r] = 0.f;

  for (int hc = 0; hc < 8; ++hc) {
    const unsigned short* wc1 = we + (size_t)hc * 16 * 512 + l * 8;           // w1 frags
    const unsigned short* wc2 = we + (size_t)(128 + hc * 16) * 512 + l * 8;   // w2 frags
    #pragma unroll
    for (int t = 0; t < 2; ++t) {
      // GEMM1 (swapped): H^T(32h x 32m) over K=128 d
      f32x16 a1;
      #pragma unroll
      for (int r = 0; r < 16; ++r) a1[r] = 0.f;
      #pragma unroll
      for (int ks = 0; ks < 8; ++ks) {
        short8 wf = *(const short8*)(wc1 + (t * 8 + ks) * 512);
        a1 = __builtin_amdgcn_mfma_f32_32x32x16_bf16(wf, xa[ks], a1, 0, 0, 0);
      }
      // gelu (lane-local) + pack into GEMM2 A-frags; feed GEMM2
      #pragma unroll
      for (int s2 = 0; s2 < 2; ++s2) {
        short8 hf8;
        #pragma unroll
        for (int j = 0; j < 8; ++j) {
          int r = (j & 3) | (s2 << 2) | ((j >> 2) << 3);
          float v = a1[r];
          float g = 0.5f * v * (1.0f + fast_erf(v * 0.70710678118654752f));
          hf8[j] = (short)f2bf(g);
        }
        int s = 2 * t + s2;
        #pragma unroll
        for (int dt = 0; dt < 4; ++dt) {
          short8 wf = *(const short8*)(wc2 + (s * 4 + dt) * 512);
          acc2[dt] = __builtin_amdgcn_mfma_f32_32x32x16_bf16(hf8, wf, acc2[dt], 0, 0, 0);
        }
      }
    }
  }

  // epilogue: scatter (score == 1.0 for top-1 softmax)
  #pragma unroll
  for (int reg = 0; reg < 16; ++reg) {
    int m = (reg & 3) + 8 * (reg >> 2) + 4 * hi;
    int ridx = mb + m;
    if (ridx < cnt) {
      int grow = rows[e * NB + ridx];
      float* op = out + (size_t)grow * DD + lc;
      op[0]  = acc2[0][reg];
      op[32] = acc2[1][reg];
      op[64] = acc2[2][reg];
      op[96] = acc2[3][reg];
    }
  }
}

extern "C" void kernel_launch(void* const* d_in, const int* in_sizes, int n_in,
                              void* d_out, int out_size, void* d_ws, size_t ws_size,
                              hipStream_t stream) {
  const float* x  = (const float*)d_in[0];
  const float* w1 = (const float*)d_in[1];
  const float* w2 = (const float*)d_in[2];
  const float* wg = (const float*)d_in[3];
  const float* bg = (const float*)d_in[4];
  float* out = (float*)d_out;

  // workspace: [0,64) counts ; [1024, +2MB) rows ; wP bf16 4MB (fragment-major)
  int* counts = (int*)d_ws;
  int* rows   = (int*)((char*)d_ws + 1024);
  unsigned short* wP = (unsigned short*)((char*)d_ws + 1024 + (size_t)EE * NB * 4);

  hipMemsetAsync(d_ws, 0, 64, stream);
  hipLaunchKernelGGL(prep_kernel, dim3(1024), dim3(256), 0, stream,
                     x, wg, bg, w1, w2, counts, rows, wP);
  hipLaunchKernelGGL(moe_gemm, dim3(EE, NB / TM), dim3(128), 0, stream,
                     x, wP, counts, rows, out);
}